// Round 1
// baseline (292.657 us; speedup 1.0000x reference)
//
#include <hip/hip_runtime.h>
#include <math.h>

// Fused WindowRegionDetector:
//  lum -> box15(mean) -> box15((lum-mean)^2)=var -> masks -> clip -> avgpool5
// One block computes an 80x80 output tile fully in LDS with separable
// sliding-window passes. Zero padding semantics match the reference:
//  - box filters: zero-pad lum / d outside image, always divide by 225
//  - d=(lum-mean)^2 and combined are forced to 0 outside the image
//  - avg_pool2d count_include_pad=True: always divide by 25

#define BLOCK 512
constexpr int T   = 80;        // output tile
constexpr int RL  = T + 32;    // 112: lum region (halo 16)
constexpr int RD  = T + 18;    // 98:  d/mean region (halo 9)
constexpr int RC  = T + 4;     // 84:  combined region (halo 2)
constexpr int LST = RL + 1;    // 113 (odd stride, no bank conflicts)
constexpr int S1  = RD + 1;    // 99  tmp1 stride (hbox1 out)
constexpr int SD  = RD + 1;    // 99  d stride
constexpr int S1B = RC + 1;    // 85  tmp1 stride (hbox2 out)
constexpr int SC  = RC + 1;    // 85  combined stride
constexpr int SP  = T + 1;     // 81  pooltmp stride

__device__ __forceinline__ float sig(float x) {
    return 1.0f / (1.0f + __expf(-x));
}

__global__ __launch_bounds__(BLOCK, 1)
void wrd_kernel(const float* __restrict__ img, float* __restrict__ out) {
    __shared__ float sL[RL * LST];   // 112*113*4 = 50,624 B  (lum)
    __shared__ float sT1[RL * S1];   // 112* 99*4 = 44,352 B  (hbox out, reused 3x)
    __shared__ float sT2[RD * SD];   //  98* 99*4 = 38,808 B  (d, then combined)

    const int tx = blockIdx.x, ty = blockIdx.y, b = blockIdx.z;
    const int ox = tx * T, oy = ty * T;
    const int tid = threadIdx.x;

    const float* pR = img + (size_t)b * 3u * 1048576u;
    const float* pG = pR + 1048576;
    const float* pB = pR + 2097152;

    // ---- step 1: luminance region -> sL (zero outside image) ----
    for (int p = tid; p < RL * RL; p += BLOCK) {
        int r = p / RL, c = p - r * RL;
        int gy = oy - 16 + r, gx = ox - 16 + c;
        float l = 0.f;
        if ((unsigned)gy < 1024u && (unsigned)gx < 1024u) {
            int idx = gy * 1024 + gx;
            l = 0.299f * pR[idx] + 0.587f * pG[idx] + 0.114f * pB[idx];
        }
        sL[r * LST + c] = l;
    }
    __syncthreads();

    // ---- step 2: horizontal box15 of lum -> sT1 [RL][RD] ----
    {
        constexpr int NS = 4, SEG = (RD + NS - 1) / NS;   // 25
        if (tid < RL * NS) {
            int row = tid % RL, seg = tid / RL;
            int c0 = seg * SEG;
            int len = min(SEG, RD - c0);
            const float* base = &sL[row * LST];
            float* o = &sT1[row * S1];
            float s = 0.f;
            #pragma unroll
            for (int k = 0; k < 15; ++k) s += base[c0 + k];
            o[c0] = s;
            for (int j = 1; j < len; ++j) {
                s += base[c0 + j + 14] - base[c0 + j - 1];
                o[c0 + j] = s;
            }
        }
    }
    __syncthreads();

    // ---- step 3: vertical box15 -> mean; d=(lum-mean)^2 -> sT2 [RD][RD] ----
    {
        constexpr int NS = 4, SEG = (RD + NS - 1) / NS;   // 25
        if (tid < RD * NS) {
            int col = tid % RD, seg = tid / RD;
            int r0 = seg * SEG;
            int len = min(SEG, RD - r0);
            float s = 0.f;
            #pragma unroll
            for (int k = 0; k < 15; ++k) s += sT1[(r0 + k) * S1 + col];
            for (int i = 0; i < len; ++i) {
                int row = r0 + i;
                float mean = s * (1.f / 225.f);
                int gy = oy - 9 + row, gx = ox - 9 + col;
                float d = 0.f;
                if ((unsigned)gy < 1024u && (unsigned)gx < 1024u) {
                    float l = sL[(row + 7) * LST + (col + 7)];
                    float t = l - mean;
                    d = t * t;
                }
                sT2[row * SD + col] = d;
                if (i + 1 < len)
                    s += sT1[(row + 15) * S1 + col] - sT1[row * S1 + col];
            }
        }
    }
    __syncthreads();

    // ---- step 4: horizontal box15 of d -> sT1 as [RD][S1B] ----
    {
        constexpr int NS = 4, SEG = (RC + NS - 1) / NS;   // 21
        if (tid < RD * NS) {
            int row = tid % RD, seg = tid / RD;
            int c0 = seg * SEG;
            int len = min(SEG, RC - c0);
            const float* base = &sT2[row * SD];
            float* o = &sT1[row * S1B];
            float s = 0.f;
            #pragma unroll
            for (int k = 0; k < 15; ++k) s += base[c0 + k];
            o[c0] = s;
            for (int j = 1; j < len; ++j) {
                s += base[c0 + j + 14] - base[c0 + j - 1];
                o[c0 + j] = s;
            }
        }
    }
    __syncthreads();

    // ---- step 5: vertical box15 -> var; combined -> sT2 as [RC][SC] ----
    {
        constexpr int NS = 4, SEG = (RC + NS - 1) / NS;   // 21
        if (tid < RC * NS) {
            int col = tid % RC, seg = tid / RC;
            int r0 = seg * SEG;
            int len = min(SEG, RC - r0);
            float s = 0.f;
            #pragma unroll
            for (int k = 0; k < 15; ++k) s += sT1[(r0 + k) * S1B + col];
            for (int i = 0; i < len; ++i) {
                int row = r0 + i;
                float var = s * (1.f / 225.f);
                int gy = oy - 2 + row, gx = ox - 2 + col;
                float comb = 0.f;
                if ((unsigned)gy < 1024u && (unsigned)gx < 1024u) {
                    float cm = sig(var * 50.f - 0.5f);
                    float l = sL[(row + 14) * LST + (col + 14)];
                    float bm = sig((l - 0.7f) * 10.f);
                    int idx = gy * 1024 + gx;
                    float r_ = pR[idx], g_ = pG[idx], b_ = pB[idx];
                    float mx = fmaxf(r_, fmaxf(g_, b_));
                    float mn = fminf(r_, fminf(g_, b_));
                    float sat = (mx - mn) / (mx + 1e-8f);
                    float lsm = sig((0.3f - sat) * 10.f);
                    comb = bm + 0.5f * cm * lsm;
                    comb = fminf(fmaxf(comb, 0.f), 1.f);
                }
                sT2[row * SC + col] = comb;
                if (i + 1 < len)
                    s += sT1[(row + 15) * S1B + col] - sT1[row * S1B + col];
            }
        }
    }
    __syncthreads();

    // ---- step 6a: horizontal pool5 of combined -> sT1 as [RC][SP] ----
    {
        constexpr int NS = 4, SEG = (T + NS - 1) / NS;    // 20
        if (tid < RC * NS) {
            int row = tid % RC, seg = tid / RC;
            int c0 = seg * SEG;
            int len = min(SEG, T - c0);
            const float* base = &sT2[row * SC];
            float* o = &sT1[row * SP];
            float s = 0.f;
            #pragma unroll
            for (int k = 0; k < 5; ++k) s += base[c0 + k];
            o[c0] = s;
            for (int j = 1; j < len; ++j) {
                s += base[c0 + j + 4] - base[c0 + j - 1];
                o[c0 + j] = s;
            }
        }
    }
    __syncthreads();

    // ---- step 6b: vertical pool5 -> global out ----
    {
        constexpr int NS = 4, SEG = (T + NS - 1) / NS;    // 20
        if (tid < T * NS) {
            int col = tid % T, seg = tid / T;
            int r0 = seg * SEG;
            int len = min(SEG, T - r0);
            float s = 0.f;
            #pragma unroll
            for (int k = 0; k < 5; ++k) s += sT1[(r0 + k) * SP + col];
            float* po = out + (size_t)b * 1048576u;
            for (int i = 0; i < len; ++i) {
                int row = r0 + i;
                int gy = oy + row, gx = ox + col;
                if (gy < 1024 && gx < 1024)
                    po[gy * 1024 + gx] = s * (1.f / 25.f);
                if (i + 1 < len)
                    s += sT1[(row + 5) * SP + col] - sT1[row * SP + col];
            }
        }
    }
}

extern "C" void kernel_launch(void* const* d_in, const int* in_sizes, int n_in,
                              void* d_out, int out_size, void* d_ws, size_t ws_size,
                              hipStream_t stream) {
    const float* img = (const float*)d_in[0];
    float* out = (float*)d_out;
    int Bn = in_sizes[0] / (3 * 1024 * 1024);
    dim3 grid((1024 + T - 1) / T, (1024 + T - 1) / T, Bn);
    hipLaunchKernelGGL(wrd_kernel, grid, dim3(BLOCK), 0, stream, img, out);
}

// Round 2
// 211.659 us; speedup vs baseline: 1.3827x; 1.3827x over previous
//
#include <hip/hip_runtime.h>
#include <math.h>

// Fused WindowRegionDetector, round 2:
//  - T=64 tile, BLOCK=512, LDS 67.5 KB -> 2 blocks/CU (16 waves, 50% occ)
//  - sL aliased with d/combined buffer; lum recomputed from img (L2-hit)
//    in phases 3 and 5 (phase 5 already loads rgb for saturation -> free)
//  - every phase single-round with >=476/512 threads active
// Semantics: box15 zero-padded, /225 always; d and combined forced 0 outside
// image; avgpool5 count_include_pad -> /25 always.

#define BLOCK 512
constexpr int T   = 64;
constexpr int RL  = T + 32;    // 96  lum region (halo 16)
constexpr int RD  = T + 18;    // 82  d/mean region (halo 9)
constexpr int RC  = T + 4;     // 68  combined region (halo 2)
constexpr int LST = RL + 1;    // 97
constexpr int S1  = RD + 1;    // 83  (hbox1 out, in sBuf1)
constexpr int SD  = RD + 1;    // 83  (d, in sBuf0)
constexpr int S1B = RC + 1;    // 69  (hbox2 out, in sBuf1)
constexpr int SC  = RC + 1;    // 69  (combined, in sBuf0)
constexpr int SP  = T + 1;     // 65  (pool tmp, in sBuf1)

__device__ __forceinline__ float sig(float x) {
    return 1.0f / (1.0f + __expf(-x));
}

__global__ __launch_bounds__(BLOCK, 4)
void wrd_kernel(const float* __restrict__ img, float* __restrict__ out) {
    __shared__ float sBuf0[RL * LST];  // 96*97*4 = 37,248 B : lum, then d, then combined
    __shared__ float sBuf1[RL * S1];   // 96*83*4 = 31,872 B : hbox outs, pool tmp

    const int ox = blockIdx.x * T, oy = blockIdx.y * T;
    const int b = blockIdx.z;
    const int tid = threadIdx.x;

    const float* pR = img + (size_t)b * 3u * 1048576u;
    const float* pG = pR + 1048576;
    const float* pB = pR + 2097152;

    // ---- phase 1: luminance region -> sBuf0 (zero outside image) ----
    #pragma unroll
    for (int p = tid; p < RL * RL; p += BLOCK) {
        int r = p / RL, c = p - r * RL;
        int gy = oy - 16 + r, gx = ox - 16 + c;
        float l = 0.f;
        if ((unsigned)gy < 1024u && (unsigned)gx < 1024u) {
            int idx = gy * 1024 + gx;
            l = 0.299f * pR[idx] + 0.587f * pG[idx] + 0.114f * pB[idx];
        }
        sBuf0[r * LST + c] = l;
    }
    __syncthreads();

    // ---- phase 2: horizontal box15 of lum -> sBuf1 [RL][RD] ----
    {
        constexpr int NS = 5, SEG = (RD + NS - 1) / NS;   // 17 ; 480 threads
        if (tid < RL * NS) {
            int row = tid % RL, seg = tid / RL;
            int c0 = seg * SEG;
            int len = min(SEG, RD - c0);
            const float* base = &sBuf0[row * LST];
            float* o = &sBuf1[row * S1];
            float s = 0.f;
            #pragma unroll
            for (int k = 0; k < 15; ++k) s += base[c0 + k];
            o[c0] = s;
            for (int j = 1; j < len; ++j) {
                s += base[c0 + j + 14] - base[c0 + j - 1];
                o[c0 + j] = s;
            }
        }
    }
    __syncthreads();

    // ---- phase 3: vertical box15 -> mean; d=(lum-mean)^2 -> sBuf0 [RD][SD] ----
    // (overwrites lum region; lum recomputed from img, L2-hot)
    {
        constexpr int NS = 6, SEG = (RD + NS - 1) / NS;   // 14 ; 492 threads
        if (tid < RD * NS) {
            int col = tid % RD, seg = tid / RD;
            int r0 = seg * SEG;
            int len = min(SEG, RD - r0);
            float s = 0.f;
            #pragma unroll
            for (int k = 0; k < 15; ++k) s += sBuf1[(r0 + k) * S1 + col];
            for (int i = 0; i < len; ++i) {
                int row = r0 + i;
                float mean = s * (1.f / 225.f);
                int gy = oy - 9 + row, gx = ox - 9 + col;
                float d = 0.f;
                if ((unsigned)gy < 1024u && (unsigned)gx < 1024u) {
                    int idx = gy * 1024 + gx;
                    float l = 0.299f * pR[idx] + 0.587f * pG[idx] + 0.114f * pB[idx];
                    float t = l - mean;
                    d = t * t;
                }
                sBuf0[row * SD + col] = d;
                if (i + 1 < len)
                    s += sBuf1[(row + 15) * S1 + col] - sBuf1[row * S1 + col];
            }
        }
    }
    __syncthreads();

    // ---- phase 4: horizontal box15 of d -> sBuf1 [RD][S1B] ----
    {
        constexpr int NS = 6, SEG = (RC + NS - 1) / NS;   // 12 ; 492 threads
        if (tid < RD * NS) {
            int row = tid % RD, seg = tid / RD;
            int c0 = seg * SEG;
            int len = min(SEG, RC - c0);
            const float* base = &sBuf0[row * SD];
            float* o = &sBuf1[row * S1B];
            float s = 0.f;
            #pragma unroll
            for (int k = 0; k < 15; ++k) s += base[c0 + k];
            o[c0] = s;
            for (int j = 1; j < len; ++j) {
                s += base[c0 + j + 14] - base[c0 + j - 1];
                o[c0 + j] = s;
            }
        }
    }
    __syncthreads();

    // ---- phase 5: vertical box15 -> var; combined -> sBuf0 [RC][SC] ----
    {
        constexpr int NS = 7, SEG = (RC + NS - 1) / NS;   // 10 ; 476 threads
        if (tid < RC * NS) {
            int col = tid % RC, seg = tid / RC;
            int r0 = seg * SEG;
            int len = min(SEG, RC - r0);
            float s = 0.f;
            #pragma unroll
            for (int k = 0; k < 15; ++k) s += sBuf1[(r0 + k) * S1B + col];
            for (int i = 0; i < len; ++i) {
                int row = r0 + i;
                float var = s * (1.f / 225.f);
                int gy = oy - 2 + row, gx = ox - 2 + col;
                float comb = 0.f;
                if ((unsigned)gy < 1024u && (unsigned)gx < 1024u) {
                    int idx = gy * 1024 + gx;
                    float r_ = pR[idx], g_ = pG[idx], b_ = pB[idx];
                    float l = 0.299f * r_ + 0.587f * g_ + 0.114f * b_;
                    float cm = sig(var * 50.f - 0.5f);
                    float bm = sig((l - 0.7f) * 10.f);
                    float mx = fmaxf(r_, fmaxf(g_, b_));
                    float mn = fminf(r_, fminf(g_, b_));
                    float sat = (mx - mn) / (mx + 1e-8f);
                    float lsm = sig((0.3f - sat) * 10.f);
                    comb = bm + 0.5f * cm * lsm;
                    comb = fminf(fmaxf(comb, 0.f), 1.f);
                }
                sBuf0[row * SC + col] = comb;
                if (i + 1 < len)
                    s += sBuf1[(row + 15) * S1B + col] - sBuf1[row * S1B + col];
            }
        }
    }
    __syncthreads();

    // ---- phase 6a: horizontal pool5 of combined -> sBuf1 [RC][SP] ----
    {
        constexpr int NS = 7, SEG = (T + NS - 1) / NS;    // 10 ; 476 threads
        if (tid < RC * NS) {
            int row = tid % RC, seg = tid / RC;
            int c0 = seg * SEG;
            int len = min(SEG, T - c0);
            const float* base = &sBuf0[row * SC];
            float* o = &sBuf1[row * SP];
            float s = 0.f;
            #pragma unroll
            for (int k = 0; k < 5; ++k) s += base[c0 + k];
            o[c0] = s;
            for (int j = 1; j < len; ++j) {
                s += base[c0 + j + 4] - base[c0 + j - 1];
                o[c0 + j] = s;
            }
        }
    }
    __syncthreads();

    // ---- phase 6b: vertical pool5 -> global out ----
    {
        constexpr int NS = 8, SEG = (T + NS - 1) / NS;    // 8 ; 512 threads
        if (tid < T * NS) {
            int col = tid % T, seg = tid / T;
            int r0 = seg * SEG;
            int len = min(SEG, T - r0);
            float s = 0.f;
            #pragma unroll
            for (int k = 0; k < 5; ++k) s += sBuf1[(r0 + k) * SP + col];
            float* po = out + (size_t)b * 1048576u;
            for (int i = 0; i < len; ++i) {
                int row = r0 + i;
                po[(oy + row) * 1024 + (ox + col)] = s * (1.f / 25.f);
                if (i + 1 < len)
                    s += sBuf1[(row + 5) * SP + col] - sBuf1[row * SP + col];
            }
        }
    }
}

extern "C" void kernel_launch(void* const* d_in, const int* in_sizes, int n_in,
                              void* d_out, int out_size, void* d_ws, size_t ws_size,
                              hipStream_t stream) {
    const float* img = (const float*)d_in[0];
    float* out = (float*)d_out;
    int Bn = in_sizes[0] / (3 * 1024 * 1024);
    dim3 grid(1024 / T, 1024 / T, Bn);
    hipLaunchKernelGGL(wrd_kernel, grid, dim3(BLOCK), 0, stream, img, out);
}

// Round 3
// 137.968 us; speedup vs baseline: 2.1212x; 1.5341x over previous
//
#include <hip/hip_runtime.h>
#include <math.h>

// Fused WindowRegionDetector, round 3: fully vectorized LDS pipeline.
//  lum(bf16) -> hbox15 -> vbox15(mean)+d(bf16) -> hbox15 -> vbox15(var)
//   -> masks/comb(bf16) -> hpool5 -> vpool5 -> out
// T=64 tile, BLOCK=512, LDS 76448 B -> 2 blocks/CU.
// Region coords: r,c in [0,96) <-> img (oy-16+r, ox-16+c).
// hboxlum[r][j] = sum lum[r][j..j+14]            (96 x 84, cols 82,83 junk)
// d[r][j] = (lum[r+7][j+7] - mean)^2             (82 x 82) bf16
// hboxd[r][j] = sum d[r][j..j+14]                (82 x 68)
// comb[r][j] = f(var, lum[r+14][j+14], img)      (68 x 68) bf16
// hpool[r][j] = sum comb[r][j..j+4]              (68 x 64)
// out[r][j] = sum hpool[r..r+4][j] / 25          (64 x 64)
// Semantics: boxes zero-padded /225 always; d, comb forced 0 outside image;
// avgpool count_include_pad /25 always.

#define BLOCK 512
typedef unsigned short u16;

#define SLUM_S 104   // u16 stride, 96 rows  (208 B/row, 16-aligned)
#define ST1_S  84    // f32 stride, 96 rows  (336 B/row, 16-aligned)
#define SD_S   88    // u16 stride, 82 rows  (176 B/row, 16-aligned)
#define SC_S   72    // u16 stride, 68 rows  (144 B/row, 16-aligned)

__device__ __forceinline__ float bf2f(u16 h) {
    return __uint_as_float(((unsigned)h) << 16);
}
__device__ __forceinline__ float blo(unsigned u) { return __uint_as_float(u << 16); }
__device__ __forceinline__ float bhi(unsigned u) { return __uint_as_float(u & 0xffff0000u); }
__device__ __forceinline__ u16 f2bf(float f) {   // round-to-nearest-even
    unsigned u = __float_as_uint(f);
    return (u16)((u + 0x7fffu + ((u >> 16) & 1u)) >> 16);
}
__device__ __forceinline__ float sigf(float x) { return 1.0f / (1.0f + __expf(-x)); }
__device__ __forceinline__ float clamp01(float x) { return fminf(fmaxf(x, 0.f), 1.f); }
__device__ __forceinline__ void unp8(uint4 v, float* o) {
    o[0] = blo(v.x); o[1] = bhi(v.x); o[2] = blo(v.y); o[3] = bhi(v.y);
    o[4] = blo(v.z); o[5] = bhi(v.z); o[6] = blo(v.w); o[7] = bhi(v.w);
}

__global__ __launch_bounds__(BLOCK, 4)
void wrd_kernel(const float* __restrict__ img, float* __restrict__ out) {
    __shared__ __align__(16) u16  sLum[96 * SLUM_S];   // 19968 B
    __shared__ __align__(16) float sT1[96 * ST1_S];    // 32256 B
    __shared__ __align__(16) u16  sD[82 * SD_S];       // 14432 B
    __shared__ __align__(16) u16  sComb[68 * SC_S];    //  9792 B

    const int tid = threadIdx.x;
    // XCD-bijective swizzle: each XCD gets a contiguous raster chunk of tiles
    int bid = blockIdx.x;
    int nwg = gridDim.x;
    int flat;
    if ((nwg & 7) == 0) { int cpx = nwg >> 3; flat = (bid & 7) * cpx + (bid >> 3); }
    else flat = bid;
    const int b  = flat >> 8;          // 256 tiles per image (16x16)
    const int t  = flat & 255;
    const int oy = (t >> 4) * 64, ox = (t & 15) * 64;

    const float* pR = img + (size_t)b * 3u * 1048576u;
    const float* pG = pR + 1048576;
    const float* pB = pR + 2097152;

    const float C225 = 1.f / 225.f;

    // ---- P1: lum (bf16) for region 96x96; zero outside image ----
    for (int task = tid; task < 96 * 24; task += BLOCK) {
        int r = task / 24, q = task % 24;
        int gy = oy - 16 + r;
        int gx = ox - 16 + 4 * q;          // quad fully in or fully out
        float l0 = 0.f, l1 = 0.f, l2 = 0.f, l3 = 0.f;
        if ((unsigned)gy < 1024u && (unsigned)gx < 1024u) {
            int idx = gy * 1024 + gx;
            float4 R = *(const float4*)&pR[idx];
            float4 G = *(const float4*)&pG[idx];
            float4 B = *(const float4*)&pB[idx];
            l0 = fmaf(0.299f, R.x, fmaf(0.587f, G.x, 0.114f * B.x));
            l1 = fmaf(0.299f, R.y, fmaf(0.587f, G.y, 0.114f * B.y));
            l2 = fmaf(0.299f, R.z, fmaf(0.587f, G.z, 0.114f * B.z));
            l3 = fmaf(0.299f, R.w, fmaf(0.587f, G.w, 0.114f * B.w));
        }
        *(ushort4*)&sLum[r * SLUM_S + 4 * q] =
            make_ushort4(f2bf(l0), f2bf(l1), f2bf(l2), f2bf(l3));
    }
    __syncthreads();

    // ---- P2: hbox15(lum) -> sT1 raw sums; 96 rows x 7 groups of 12 ----
    for (int task = tid; task < 96 * 7; task += BLOCK) {
        int r = task / 7, g = task % 7;
        int s0 = 12 * g;
        int c0 = s0 & ~7;
        const u16* lr = &sLum[r * SLUM_S + c0];
        float lv[32];
        unp8(*(const uint4*)(lr),      lv);
        unp8(*(const uint4*)(lr + 8),  lv + 8);
        unp8(*(const uint4*)(lr + 16), lv + 16);
        unp8(*(const uint4*)(lr + 24), lv + 24);
        if (s0 & 4) {
            #pragma unroll
            for (int i = 0; i < 28; ++i) lv[i] = lv[i + 4];
        }
        float o[12];
        float s = 0.f;
        #pragma unroll
        for (int k = 0; k < 15; ++k) s += lv[k];
        o[0] = s;
        #pragma unroll
        for (int j = 1; j < 12; ++j) { s += lv[j + 14] - lv[j - 1]; o[j] = s; }
        float* orow = &sT1[r * ST1_S + s0];
        *(float4*)(orow)     = make_float4(o[0], o[1], o[2], o[3]);
        *(float4*)(orow + 4) = make_float4(o[4], o[5], o[6], o[7]);
        *(float4*)(orow + 8) = make_float4(o[8], o[9], o[10], o[11]);
    }
    __syncthreads();

    // ---- P3: mean = vbox15(hboxlum)/225; d=(lum-mean)^2 -> sD bf16 ----
    // 41 row-pairs x 21 quads; d rows r, r+1
    for (int task = tid; task < 41 * 21; task += BLOCK) {
        int rp = task / 21, q = task % 21;
        int r = 2 * rp;
        const float* tcol = &sT1[r * ST1_S + 4 * q];
        float4 a0 = *(const float4*)(tcol);
        float sx = a0.x, sy = a0.y, sz = a0.z, sw = a0.w;
        #pragma unroll
        for (int k = 1; k < 15; ++k) {
            float4 h = *(const float4*)(tcol + k * ST1_S);
            sx += h.x; sy += h.y; sz += h.z; sw += h.w;
        }
        float4 h15 = *(const float4*)(tcol + 15 * ST1_S);
        float m0x = sx * C225, m0y = sy * C225, m0z = sz * C225, m0w = sw * C225;
        float m1x = (sx - a0.x + h15.x) * C225, m1y = (sy - a0.y + h15.y) * C225;
        float m1z = (sz - a0.z + h15.z) * C225, m1w = (sw - a0.w + h15.w) * C225;
        // lum rows r+7, r+8 ; cols 4q+7..4q+10
        const u16* l0 = &sLum[(r + 7) * SLUM_S + 4 * q];
        ushort4 La = *(const ushort4*)(l0 + 4);
        ushort4 Lb = *(const ushort4*)(l0 + 8);
        ushort4 Lc = *(const ushort4*)(l0 + SLUM_S + 4);
        ushort4 Ld = *(const ushort4*)(l0 + SLUM_S + 8);
        float L00 = bf2f(La.w), L01 = bf2f(Lb.x), L02 = bf2f(Lb.y), L03 = bf2f(Lb.z);
        float L10 = bf2f(Lc.w), L11 = bf2f(Ld.x), L12 = bf2f(Ld.y), L13 = bf2f(Ld.z);
        int gy0 = oy - 9 + r;
        int gx0 = ox - 9 + 4 * q;
        bool vy0 = (unsigned)gy0 < 1024u, vy1 = (unsigned)(gy0 + 1) < 1024u;
        bool v0 = (unsigned)(gx0 + 0) < 1024u, v1 = (unsigned)(gx0 + 1) < 1024u;
        bool v2 = (unsigned)(gx0 + 2) < 1024u, v3 = (unsigned)(gx0 + 3) < 1024u;
        float t0, d00 = 0.f, d01 = 0.f, d02 = 0.f, d03 = 0.f;
        float d10 = 0.f, d11 = 0.f, d12 = 0.f, d13 = 0.f;
        if (vy0) {
            if (v0) { t0 = L00 - m0x; d00 = t0 * t0; }
            if (v1) { t0 = L01 - m0y; d01 = t0 * t0; }
            if (v2) { t0 = L02 - m0z; d02 = t0 * t0; }
            if (v3) { t0 = L03 - m0w; d03 = t0 * t0; }
        }
        if (vy1) {
            if (v0) { t0 = L10 - m1x; d10 = t0 * t0; }
            if (v1) { t0 = L11 - m1y; d11 = t0 * t0; }
            if (v2) { t0 = L12 - m1z; d12 = t0 * t0; }
            if (v3) { t0 = L13 - m1w; d13 = t0 * t0; }
        }
        *(ushort4*)&sD[r * SD_S + 4 * q] =
            make_ushort4(f2bf(d00), f2bf(d01), f2bf(d02), f2bf(d03));
        *(ushort4*)&sD[(r + 1) * SD_S + 4 * q] =
            make_ushort4(f2bf(d10), f2bf(d11), f2bf(d12), f2bf(d13));
    }
    __syncthreads();

    // ---- P4: hbox15(d) -> sT1 raw sums (hboxd 82x68); 82 rows x 6 groups ----
    for (int task = tid; task < 82 * 6; task += BLOCK) {
        int r = task / 6, g = task % 6;
        int s0 = 12 * g;
        int c0 = s0 & ~7;
        const u16* dr = &sD[r * SD_S + c0];
        float lv[32];
        unp8(*(const uint4*)(dr),      lv);
        unp8(*(const uint4*)(dr + 8),  lv + 8);
        unp8(*(const uint4*)(dr + 16), lv + 16);
        unp8(*(const uint4*)(dr + 24), lv + 24);
        if (s0 & 4) {
            #pragma unroll
            for (int i = 0; i < 28; ++i) lv[i] = lv[i + 4];
        }
        float o[12];
        float s = 0.f;
        #pragma unroll
        for (int k = 0; k < 15; ++k) s += lv[k];
        o[0] = s;
        #pragma unroll
        for (int j = 1; j < 12; ++j) { s += lv[j + 14] - lv[j - 1]; o[j] = s; }
        float* orow = &sT1[r * ST1_S + s0];
        *(float4*)(orow)     = make_float4(o[0], o[1], o[2], o[3]);
        *(float4*)(orow + 4) = make_float4(o[4], o[5], o[6], o[7]);
        if (g < 5) *(float4*)(orow + 8) = make_float4(o[8], o[9], o[10], o[11]);
    }
    __syncthreads();

    // ---- P5: var = vbox15(hboxd)/225; comb -> sComb bf16 ----
    // 34 row-pairs x 17 quads
    for (int task = tid; task < 34 * 17; task += BLOCK) {
        int rp = task / 17, q = task % 17;
        int r = 2 * rp;
        const float* tcol = &sT1[r * ST1_S + 4 * q];
        float4 a0 = *(const float4*)(tcol);
        float sx = a0.x, sy = a0.y, sz = a0.z, sw = a0.w;
        #pragma unroll
        for (int k = 1; k < 15; ++k) {
            float4 h = *(const float4*)(tcol + k * ST1_S);
            sx += h.x; sy += h.y; sz += h.z; sw += h.w;
        }
        float4 h15 = *(const float4*)(tcol + 15 * ST1_S);
        float cm0x = sigf(sx * C225 * 50.f - 0.5f);
        float cm0y = sigf(sy * C225 * 50.f - 0.5f);
        float cm0z = sigf(sz * C225 * 50.f - 0.5f);
        float cm0w = sigf(sw * C225 * 50.f - 0.5f);
        float cm1x = sigf((sx - a0.x + h15.x) * C225 * 50.f - 0.5f);
        float cm1y = sigf((sy - a0.y + h15.y) * C225 * 50.f - 0.5f);
        float cm1z = sigf((sz - a0.z + h15.z) * C225 * 50.f - 0.5f);
        float cm1w = sigf((sw - a0.w + h15.w) * C225 * 50.f - 0.5f);
        // bm: lum rows r+14, r+15; cols 4q+14..4q+17
        const u16* l0 = &sLum[(r + 14) * SLUM_S + 4 * q];
        ushort4 La = *(const ushort4*)(l0 + 12);
        ushort4 Lb = *(const ushort4*)(l0 + 16);
        ushort4 Lc = *(const ushort4*)(l0 + SLUM_S + 12);
        ushort4 Ld = *(const ushort4*)(l0 + SLUM_S + 16);
        float bm00 = sigf((bf2f(La.z) - 0.7f) * 10.f);
        float bm01 = sigf((bf2f(La.w) - 0.7f) * 10.f);
        float bm02 = sigf((bf2f(Lb.x) - 0.7f) * 10.f);
        float bm03 = sigf((bf2f(Lb.y) - 0.7f) * 10.f);
        float bm10 = sigf((bf2f(Lc.z) - 0.7f) * 10.f);
        float bm11 = sigf((bf2f(Lc.w) - 0.7f) * 10.f);
        float bm12 = sigf((bf2f(Ld.x) - 0.7f) * 10.f);
        float bm13 = sigf((bf2f(Ld.y) - 0.7f) * 10.f);
        // saturation from img (L2-hot re-read)
        int gy0 = oy - 2 + r;
        int gx0 = ox - 2 + 4 * q;                    // even; pairs don't straddle edge
        bool vy0 = (unsigned)gy0 < 1024u, vy1 = (unsigned)(gy0 + 1) < 1024u;
        bool va = (unsigned)gx0 < 1024u, vb = (unsigned)(gx0 + 2) < 1024u;
        float2 z2 = make_float2(0.f, 0.f);
        int i00 = gy0 * 1024 + gx0, i01 = i00 + 2;
        int i10 = i00 + 1024, i11 = i10 + 2;
        float2 Ra0 = (vy0 && va) ? *(const float2*)&pR[i00] : z2;
        float2 Rb0 = (vy0 && vb) ? *(const float2*)&pR[i01] : z2;
        float2 Ga0 = (vy0 && va) ? *(const float2*)&pG[i00] : z2;
        float2 Gb0 = (vy0 && vb) ? *(const float2*)&pG[i01] : z2;
        float2 Ba0 = (vy0 && va) ? *(const float2*)&pB[i00] : z2;
        float2 Bb0 = (vy0 && vb) ? *(const float2*)&pB[i01] : z2;
        float2 Ra1 = (vy1 && va) ? *(const float2*)&pR[i10] : z2;
        float2 Rb1 = (vy1 && vb) ? *(const float2*)&pR[i11] : z2;
        float2 Ga1 = (vy1 && va) ? *(const float2*)&pG[i10] : z2;
        float2 Gb1 = (vy1 && vb) ? *(const float2*)&pG[i11] : z2;
        float2 Ba1 = (vy1 && va) ? *(const float2*)&pB[i10] : z2;
        float2 Bb1 = (vy1 && vb) ? *(const float2*)&pB[i11] : z2;
        u16 c[8];
        #pragma unroll
        for (int e = 0; e < 4; ++e) {
            float r0, g0, b0, r1, g1, b1;
            bool vx = (e < 2) ? va : vb;
            if (e == 0) { r0 = Ra0.x; g0 = Ga0.x; b0 = Ba0.x; r1 = Ra1.x; g1 = Ga1.x; b1 = Ba1.x; }
            else if (e == 1) { r0 = Ra0.y; g0 = Ga0.y; b0 = Ba0.y; r1 = Ra1.y; g1 = Ga1.y; b1 = Ba1.y; }
            else if (e == 2) { r0 = Rb0.x; g0 = Gb0.x; b0 = Bb0.x; r1 = Rb1.x; g1 = Gb1.x; b1 = Bb1.x; }
            else { r0 = Rb0.y; g0 = Gb0.y; b0 = Bb0.y; r1 = Rb1.y; g1 = Gb1.y; b1 = Bb1.y; }
            float mx0 = fmaxf(r0, fmaxf(g0, b0)), mn0 = fminf(r0, fminf(g0, b0));
            float mx1 = fmaxf(r1, fmaxf(g1, b1)), mn1 = fminf(r1, fminf(g1, b1));
            float lsm0 = sigf((0.3f - (mx0 - mn0) / (mx0 + 1e-8f)) * 10.f);
            float lsm1 = sigf((0.3f - (mx1 - mn1) / (mx1 + 1e-8f)) * 10.f);
            float bm0 = (e == 0) ? bm00 : (e == 1) ? bm01 : (e == 2) ? bm02 : bm03;
            float bm1 = (e == 0) ? bm10 : (e == 1) ? bm11 : (e == 2) ? bm12 : bm13;
            float cm0 = (e == 0) ? cm0x : (e == 1) ? cm0y : (e == 2) ? cm0z : cm0w;
            float cm1 = (e == 0) ? cm1x : (e == 1) ? cm1y : (e == 2) ? cm1z : cm1w;
            float cb0 = (vy0 && vx) ? clamp01(bm0 + 0.5f * cm0 * lsm0) : 0.f;
            float cb1 = (vy1 && vx) ? clamp01(bm1 + 0.5f * cm1 * lsm1) : 0.f;
            c[e] = f2bf(cb0); c[e + 4] = f2bf(cb1);
        }
        *(ushort4*)&sComb[r * SC_S + 4 * q]       = make_ushort4(c[0], c[1], c[2], c[3]);
        *(ushort4*)&sComb[(r + 1) * SC_S + 4 * q] = make_ushort4(c[4], c[5], c[6], c[7]);
    }
    __syncthreads();

    // ---- P6a: hpool5(comb) -> sT1 raw sums (hpool 68x64); 68 rows x 4 groups of 16 ----
    for (int task = tid; task < 68 * 4; task += BLOCK) {
        int r = task / 4, g = task % 4;
        int s0 = 16 * g;
        const u16* cr = &sComb[r * SC_S + s0];
        float cv[24];
        unp8(*(const uint4*)(cr),      cv);
        unp8(*(const uint4*)(cr + 8),  cv + 8);
        unp8(*(const uint4*)(cr + 16), cv + 16);
        float o[16];
        float s = cv[0] + cv[1] + cv[2] + cv[3] + cv[4];
        o[0] = s;
        #pragma unroll
        for (int j = 1; j < 16; ++j) { s += cv[j + 4] - cv[j - 1]; o[j] = s; }
        float* orow = &sT1[r * ST1_S + s0];
        *(float4*)(orow)      = make_float4(o[0], o[1], o[2], o[3]);
        *(float4*)(orow + 4)  = make_float4(o[4], o[5], o[6], o[7]);
        *(float4*)(orow + 8)  = make_float4(o[8], o[9], o[10], o[11]);
        *(float4*)(orow + 12) = make_float4(o[12], o[13], o[14], o[15]);
    }
    __syncthreads();

    // ---- P6b: vpool5 -> global out; 32 row-pairs x 16 quads ----
    for (int task = tid; task < 32 * 16; task += BLOCK) {
        int rp = task / 16, q = task % 16;
        int r = 2 * rp;
        const float* tcol = &sT1[r * ST1_S + 4 * q];
        float4 h0 = *(const float4*)(tcol);
        float4 h1 = *(const float4*)(tcol + ST1_S);
        float4 h2 = *(const float4*)(tcol + 2 * ST1_S);
        float4 h3 = *(const float4*)(tcol + 3 * ST1_S);
        float4 h4 = *(const float4*)(tcol + 4 * ST1_S);
        float4 h5 = *(const float4*)(tcol + 5 * ST1_S);
        float s0x = h0.x + h1.x + h2.x + h3.x + h4.x;
        float s0y = h0.y + h1.y + h2.y + h3.y + h4.y;
        float s0z = h0.z + h1.z + h2.z + h3.z + h4.z;
        float s0w = h0.w + h1.w + h2.w + h3.w + h4.w;
        const float C25 = 1.f / 25.f;
        float* po = out + (size_t)b * 1048576u + (size_t)(oy + r) * 1024 + ox + 4 * q;
        *(float4*)po = make_float4(s0x * C25, s0y * C25, s0z * C25, s0w * C25);
        *(float4*)(po + 1024) = make_float4((s0x - h0.x + h5.x) * C25,
                                            (s0y - h0.y + h5.y) * C25,
                                            (s0z - h0.z + h5.z) * C25,
                                            (s0w - h0.w + h5.w) * C25);
    }
}

extern "C" void kernel_launch(void* const* d_in, const int* in_sizes, int n_in,
                              void* d_out, int out_size, void* d_ws, size_t ws_size,
                              hipStream_t stream) {
    const float* img = (const float*)d_in[0];
    float* out = (float*)d_out;
    int Bn = in_sizes[0] / (3 * 1024 * 1024);
    int nwg = Bn * 256;                 // 16x16 tiles of 64x64 per image
    hipLaunchKernelGGL(wrd_kernel, dim3(nwg), dim3(BLOCK), 0, stream, img, out);
}

// Round 4
// 113.756 us; speedup vs baseline: 2.5727x; 1.2128x over previous
//
#include <hip/hip_runtime.h>

// Fused WindowRegionDetector, round 4:
//  - bf16 hbox sums (sT1) + sD/sComb union -> LDS 50.1 KB -> 3 blocks/CU
//  - template<EDGE>: interior tiles (196/256) skip ALL bounds checks
//  - v_cvt_pk_bf16_f32 packing, 4-row vertical tasks, 16-wide lum loads
// Pipeline per 64x64 tile (region coords r,c in [0,96) <-> img oy-16+r, ox-16+c):
//  P1 lum bf16 96x96 -> P2 hbox15 -> P3 vbox15(mean)+d bf16 -> P4 hbox15(d)
//  -> P5 vbox15(var)+comb bf16 -> P6a hpool5 -> P6b vpool5 -> out
// Semantics: boxes zero-padded /225 always; d, comb forced 0 outside image;
// avgpool count_include_pad /25 always.

#define BLOCK 512
typedef unsigned short u16;
typedef unsigned int u32;

#define SL 104   // sLum u16 stride (208 B)
#define S1 88    // sT1 / sDC u16 stride (176 B)

__device__ __forceinline__ float blo(u32 u){ return __uint_as_float(u << 16); }
__device__ __forceinline__ float bhi(u32 u){ return __uint_as_float(u & 0xffff0000u); }
__device__ __forceinline__ float bf2f(u16 h){ return __uint_as_float(((u32)h) << 16); }
__device__ __forceinline__ u32 pk2(float lo, float hi){
    u32 r; asm("v_cvt_pk_bf16_f32 %0, %1, %2" : "=v"(r) : "v"(lo), "v"(hi)); return r;
}
__device__ __forceinline__ float sigf(float x){ return 1.f / (1.f + __expf(-x)); }
__device__ __forceinline__ float clamp01(float x){ return fminf(fmaxf(x, 0.f), 1.f); }
__device__ __forceinline__ void unp8(uint4 v, float* o){
    o[0]=blo(v.x); o[1]=bhi(v.x); o[2]=blo(v.y); o[3]=bhi(v.y);
    o[4]=blo(v.z); o[5]=bhi(v.z); o[6]=blo(v.w); o[7]=bhi(v.w);
}
__device__ __forceinline__ float satm(float r_, float g_, float b_){
    float mx = fmaxf(r_, fmaxf(g_, b_));
    float mn = fminf(r_, fminf(g_, b_));
    float sat = (mx - mn) / (mx + 1e-8f);
    return sigf((0.3f - sat) * 10.f);
}

template<bool EDGE>
__device__ __forceinline__ void body(const float* __restrict__ pR,
                                     const float* __restrict__ pG,
                                     const float* __restrict__ pB,
                                     float* __restrict__ po,
                                     int oy, int ox, int tid,
                                     u16* sLum, u16* sT1, u16* sDC)
{
    const float C225 = 1.f / 225.f;
    const float CF   = 50.f / 225.f;

    // ---- P1: lum bf16, 96 rows x 6 groups of 16 cols (576 tasks) ----
    for (int task = tid; task < 96 * 6; task += BLOCK) {
        int r = task / 6, c = task - r * 6;
        int gy = oy - 16 + r;
        int gxb = ox - 16 + 16 * c;
        u32 pk[8];
        #pragma unroll
        for (int sq = 0; sq < 4; ++sq) {
            int gx = gxb + 4 * sq;
            float l0 = 0.f, l1 = 0.f, l2 = 0.f, l3 = 0.f;
            if (!EDGE || ((unsigned)gy < 1024u && (unsigned)gx < 1024u)) {
                int idx = gy * 1024 + gx;
                float4 R  = *(const float4*)&pR[idx];
                float4 G  = *(const float4*)&pG[idx];
                float4 Bc = *(const float4*)&pB[idx];
                l0 = fmaf(0.299f, R.x, fmaf(0.587f, G.x, 0.114f * Bc.x));
                l1 = fmaf(0.299f, R.y, fmaf(0.587f, G.y, 0.114f * Bc.y));
                l2 = fmaf(0.299f, R.z, fmaf(0.587f, G.z, 0.114f * Bc.z));
                l3 = fmaf(0.299f, R.w, fmaf(0.587f, G.w, 0.114f * Bc.w));
            }
            pk[2 * sq]     = pk2(l0, l1);
            pk[2 * sq + 1] = pk2(l2, l3);
        }
        u16* dst = &sLum[r * SL + 16 * c];
        *(uint4*)dst     = make_uint4(pk[0], pk[1], pk[2], pk[3]);
        *(uint4*)(dst+8) = make_uint4(pk[4], pk[5], pk[6], pk[7]);
    }
    __syncthreads();

    // ---- P2: hbox15(lum) -> sT1 bf16; 96 rows x 7 groups of 12 (672) ----
    for (int task = tid; task < 96 * 7; task += BLOCK) {
        int r = task / 7, g = task - r * 7;
        int s0 = 12 * g, c0 = s0 & ~7;
        const u16* lr = &sLum[r * SL + c0];
        float lv[32];
        unp8(*(const uint4*)lr,        lv);
        unp8(*(const uint4*)(lr + 8),  lv + 8);
        unp8(*(const uint4*)(lr + 16), lv + 16);
        unp8(*(const uint4*)(lr + 24), lv + 24);
        if (s0 & 4) {
            #pragma unroll
            for (int i = 0; i < 28; ++i) lv[i] = lv[i + 4];
        }
        float o[12];
        float s = 0.f;
        #pragma unroll
        for (int k = 0; k < 15; ++k) s += lv[k];
        o[0] = s;
        #pragma unroll
        for (int j = 1; j < 12; ++j) { s += lv[j + 14] - lv[j - 1]; o[j] = s; }
        u16* dst = &sT1[r * S1 + s0];
        *(uint2*)dst       = make_uint2(pk2(o[0], o[1]),  pk2(o[2], o[3]));
        *(uint2*)(dst + 4) = make_uint2(pk2(o[4], o[5]),  pk2(o[6], o[7]));
        *(uint2*)(dst + 8) = make_uint2(pk2(o[8], o[9]),  pk2(o[10], o[11]));
    }
    __syncthreads();

    // ---- P3: mean = vbox15/225; d=(lum-mean)^2 bf16 -> sDC ----
    // 21 row-groups of 4 x 21 col-quads (441 tasks)
    for (int task = tid; task < 21 * 21; task += BLOCK) {
        int rg = task / 21, q = task - rg * 21;
        int r0 = 4 * rg;
        const u16* hp = &sT1[r0 * S1 + 4 * q];
        float cs0 = 0.f, cs1 = 0.f, cs2 = 0.f, cs3 = 0.f;
        float a00, a01, a02, a03, a10, a11, a12, a13, a20, a21, a22, a23;
        #pragma unroll
        for (int k = 0; k < 15; ++k) {
            uint2 v = *(const uint2*)(hp + k * S1);
            float x0 = blo(v.x), x1 = bhi(v.x), x2 = blo(v.y), x3 = bhi(v.y);
            if (k == 0) { a00 = x0; a01 = x1; a02 = x2; a03 = x3; }
            if (k == 1) { a10 = x0; a11 = x1; a12 = x2; a13 = x3; }
            if (k == 2) { a20 = x0; a21 = x1; a22 = x2; a23 = x3; }
            cs0 += x0; cs1 += x1; cs2 += x2; cs3 += x3;
        }
        auto emitD = [&](int row) {
            float m0 = cs0 * C225, m1 = cs1 * C225, m2 = cs2 * C225, m3 = cs3 * C225;
            const u16* lp = &sLum[(row + 7) * SL + 4 * q + 4];
            ushort4 A  = *(const ushort4*)lp;
            ushort4 Bv = *(const ushort4*)(lp + 4);
            float t0 = bf2f(A.w)  - m0, t1 = bf2f(Bv.x) - m1;
            float t2 = bf2f(Bv.y) - m2, t3 = bf2f(Bv.z) - m3;
            float d0 = t0 * t0, d1 = t1 * t1, d2 = t2 * t2, d3 = t3 * t3;
            if (EDGE) {
                int gy = oy - 9 + row, gx = ox - 9 + 4 * q;
                bool vy = (unsigned)gy < 1024u;
                d0 = (vy && (unsigned)(gx    ) < 1024u) ? d0 : 0.f;
                d1 = (vy && (unsigned)(gx + 1) < 1024u) ? d1 : 0.f;
                d2 = (vy && (unsigned)(gx + 2) < 1024u) ? d2 : 0.f;
                d3 = (vy && (unsigned)(gx + 3) < 1024u) ? d3 : 0.f;
            }
            *(uint2*)&sDC[row * S1 + 4 * q] = make_uint2(pk2(d0, d1), pk2(d2, d3));
        };
        emitD(r0);
        {
            uint2 v = *(const uint2*)(hp + 15 * S1);
            cs0 += blo(v.x) - a00; cs1 += bhi(v.x) - a01;
            cs2 += blo(v.y) - a02; cs3 += bhi(v.y) - a03;
        }
        emitD(r0 + 1);
        if (r0 + 2 < 82) {
            uint2 v = *(const uint2*)(hp + 16 * S1);
            cs0 += blo(v.x) - a10; cs1 += bhi(v.x) - a11;
            cs2 += blo(v.y) - a12; cs3 += bhi(v.y) - a13;
            emitD(r0 + 2);
            uint2 w = *(const uint2*)(hp + 17 * S1);
            cs0 += blo(w.x) - a20; cs1 += bhi(w.x) - a21;
            cs2 += blo(w.y) - a22; cs3 += bhi(w.y) - a23;
            emitD(r0 + 3);
        }
    }
    __syncthreads();

    // ---- P4: hbox15(d) -> sT1 bf16; 82 rows x 6 groups of 12 (492) ----
    for (int task = tid; task < 82 * 6; task += BLOCK) {
        int r = task / 6, g = task - r * 6;
        int s0 = 12 * g, c0 = s0 & ~7;
        const u16* dr = &sDC[r * S1 + c0];
        float lv[32];
        unp8(*(const uint4*)dr,        lv);
        unp8(*(const uint4*)(dr + 8),  lv + 8);
        unp8(*(const uint4*)(dr + 16), lv + 16);
        unp8(*(const uint4*)(dr + 24), lv + 24);
        if (s0 & 4) {
            #pragma unroll
            for (int i = 0; i < 28; ++i) lv[i] = lv[i + 4];
        }
        float o[12];
        float s = 0.f;
        #pragma unroll
        for (int k = 0; k < 15; ++k) s += lv[k];
        o[0] = s;
        #pragma unroll
        for (int j = 1; j < 12; ++j) { s += lv[j + 14] - lv[j - 1]; o[j] = s; }
        u16* dst = &sT1[r * S1 + s0];
        *(uint2*)dst       = make_uint2(pk2(o[0], o[1]),  pk2(o[2], o[3]));
        *(uint2*)(dst + 4) = make_uint2(pk2(o[4], o[5]),  pk2(o[6], o[7]));
        *(uint2*)(dst + 8) = make_uint2(pk2(o[8], o[9]),  pk2(o[10], o[11]));
    }
    __syncthreads();

    // ---- P5: var = vbox15/225; comb bf16 -> sDC (overwrites d) ----
    // 17 row-groups of 4 x 17 col-quads (289 tasks)
    for (int task = tid; task < 17 * 17; task += BLOCK) {
        int rg = task / 17, q = task - rg * 17;
        int r0 = 4 * rg;
        const u16* hp = &sT1[r0 * S1 + 4 * q];
        float cs0 = 0.f, cs1 = 0.f, cs2 = 0.f, cs3 = 0.f;
        float a00, a01, a02, a03, a10, a11, a12, a13, a20, a21, a22, a23;
        #pragma unroll
        for (int k = 0; k < 15; ++k) {
            uint2 v = *(const uint2*)(hp + k * S1);
            float x0 = blo(v.x), x1 = bhi(v.x), x2 = blo(v.y), x3 = bhi(v.y);
            if (k == 0) { a00 = x0; a01 = x1; a02 = x2; a03 = x3; }
            if (k == 1) { a10 = x0; a11 = x1; a12 = x2; a13 = x3; }
            if (k == 2) { a20 = x0; a21 = x1; a22 = x2; a23 = x3; }
            cs0 += x0; cs1 += x1; cs2 += x2; cs3 += x3;
        }
        auto emitC = [&](int row) {
            float cm0 = sigf(fmaf(cs0, CF, -0.5f));
            float cm1 = sigf(fmaf(cs1, CF, -0.5f));
            float cm2 = sigf(fmaf(cs2, CF, -0.5f));
            float cm3 = sigf(fmaf(cs3, CF, -0.5f));
            const u16* lp = &sLum[(row + 14) * SL + 4 * q + 12];
            ushort4 A  = *(const ushort4*)lp;
            ushort4 Bv = *(const ushort4*)(lp + 4);
            float bm0 = sigf((bf2f(A.z)  - 0.7f) * 10.f);
            float bm1 = sigf((bf2f(A.w)  - 0.7f) * 10.f);
            float bm2 = sigf((bf2f(Bv.x) - 0.7f) * 10.f);
            float bm3 = sigf((bf2f(Bv.y) - 0.7f) * 10.f);
            int gy = oy - 2 + row, gx0 = ox - 2 + 4 * q;
            int i0 = gy * 1024 + gx0;
            float2 z2 = make_float2(0.f, 0.f);
            float2 Ra, Rb, Ga, Gb, Ba, Bb;
            bool va = true, vb = true;
            if (EDGE) {
                bool vy = (unsigned)gy < 1024u;
                va = vy && (unsigned)gx0 < 1024u;
                vb = vy && (unsigned)(gx0 + 2) < 1024u;
                Ra = va ? *(const float2*)&pR[i0]     : z2;
                Rb = vb ? *(const float2*)&pR[i0 + 2] : z2;
                Ga = va ? *(const float2*)&pG[i0]     : z2;
                Gb = vb ? *(const float2*)&pG[i0 + 2] : z2;
                Ba = va ? *(const float2*)&pB[i0]     : z2;
                Bb = vb ? *(const float2*)&pB[i0 + 2] : z2;
            } else {
                Ra = *(const float2*)&pR[i0];  Rb = *(const float2*)&pR[i0 + 2];
                Ga = *(const float2*)&pG[i0];  Gb = *(const float2*)&pG[i0 + 2];
                Ba = *(const float2*)&pB[i0];  Bb = *(const float2*)&pB[i0 + 2];
            }
            float cb0 = clamp01(bm0 + 0.5f * cm0 * satm(Ra.x, Ga.x, Ba.x));
            float cb1 = clamp01(bm1 + 0.5f * cm1 * satm(Ra.y, Ga.y, Ba.y));
            float cb2 = clamp01(bm2 + 0.5f * cm2 * satm(Rb.x, Gb.x, Bb.x));
            float cb3 = clamp01(bm3 + 0.5f * cm3 * satm(Rb.y, Gb.y, Bb.y));
            if (EDGE) {
                cb0 = va ? cb0 : 0.f;  cb1 = va ? cb1 : 0.f;
                cb2 = vb ? cb2 : 0.f;  cb3 = vb ? cb3 : 0.f;
            }
            *(uint2*)&sDC[row * S1 + 4 * q] = make_uint2(pk2(cb0, cb1), pk2(cb2, cb3));
        };
        emitC(r0);
        {
            uint2 v = *(const uint2*)(hp + 15 * S1);
            cs0 += blo(v.x) - a00; cs1 += bhi(v.x) - a01;
            cs2 += blo(v.y) - a02; cs3 += bhi(v.y) - a03;
        }
        emitC(r0 + 1);
        {
            uint2 v = *(const uint2*)(hp + 16 * S1);
            cs0 += blo(v.x) - a10; cs1 += bhi(v.x) - a11;
            cs2 += blo(v.y) - a12; cs3 += bhi(v.y) - a13;
        }
        emitC(r0 + 2);
        {
            uint2 v = *(const uint2*)(hp + 17 * S1);
            cs0 += blo(v.x) - a20; cs1 += bhi(v.x) - a21;
            cs2 += blo(v.y) - a22; cs3 += bhi(v.y) - a23;
        }
        emitC(r0 + 3);
    }
    __syncthreads();

    // ---- P6a: hpool5(comb) -> sT1 bf16; 68 rows x 4 groups of 16 (272) ----
    for (int task = tid; task < 68 * 4; task += BLOCK) {
        int r = task / 4, g = task & 3;
        int s0 = 16 * g;
        const u16* cr = &sDC[r * S1 + s0];
        float cv[24];
        unp8(*(const uint4*)cr,        cv);
        unp8(*(const uint4*)(cr + 8),  cv + 8);
        unp8(*(const uint4*)(cr + 16), cv + 16);
        float o[16];
        float s = cv[0] + cv[1] + cv[2] + cv[3] + cv[4];
        o[0] = s;
        #pragma unroll
        for (int j = 1; j < 16; ++j) { s += cv[j + 4] - cv[j - 1]; o[j] = s; }
        u16* dst = &sT1[r * S1 + s0];
        *(uint4*)dst = make_uint4(pk2(o[0], o[1]), pk2(o[2], o[3]),
                                  pk2(o[4], o[5]), pk2(o[6], o[7]));
        *(uint4*)(dst + 8) = make_uint4(pk2(o[8],  o[9]),  pk2(o[10], o[11]),
                                        pk2(o[12], o[13]), pk2(o[14], o[15]));
    }
    __syncthreads();

    // ---- P6b: vpool5 -> out; 16 row-groups of 4 x 16 col-quads (256) ----
    for (int task = tid; task < 16 * 16; task += BLOCK) {
        int rg = task / 16, q = task & 15;
        int r0 = 4 * rg;
        const u16* hp = &sT1[r0 * S1 + 4 * q];
        float cs0 = 0.f, cs1 = 0.f, cs2 = 0.f, cs3 = 0.f;
        float a00, a01, a02, a03, a10, a11, a12, a13, a20, a21, a22, a23;
        #pragma unroll
        for (int k = 0; k < 5; ++k) {
            uint2 v = *(const uint2*)(hp + k * S1);
            float x0 = blo(v.x), x1 = bhi(v.x), x2 = blo(v.y), x3 = bhi(v.y);
            if (k == 0) { a00 = x0; a01 = x1; a02 = x2; a03 = x3; }
            if (k == 1) { a10 = x0; a11 = x1; a12 = x2; a13 = x3; }
            if (k == 2) { a20 = x0; a21 = x1; a22 = x2; a23 = x3; }
            cs0 += x0; cs1 += x1; cs2 += x2; cs3 += x3;
        }
        const float C25 = 1.f / 25.f;
        float* o0 = po + (size_t)(oy + r0) * 1024 + ox + 4 * q;
        *(float4*)o0 = make_float4(cs0 * C25, cs1 * C25, cs2 * C25, cs3 * C25);
        {
            uint2 v = *(const uint2*)(hp + 5 * S1);
            cs0 += blo(v.x) - a00; cs1 += bhi(v.x) - a01;
            cs2 += blo(v.y) - a02; cs3 += bhi(v.y) - a03;
        }
        *(float4*)(o0 + 1024) = make_float4(cs0 * C25, cs1 * C25, cs2 * C25, cs3 * C25);
        {
            uint2 v = *(const uint2*)(hp + 6 * S1);
            cs0 += blo(v.x) - a10; cs1 += bhi(v.x) - a11;
            cs2 += blo(v.y) - a12; cs3 += bhi(v.y) - a13;
        }
        *(float4*)(o0 + 2048) = make_float4(cs0 * C25, cs1 * C25, cs2 * C25, cs3 * C25);
        {
            uint2 v = *(const uint2*)(hp + 7 * S1);
            cs0 += blo(v.x) - a20; cs1 += bhi(v.x) - a21;
            cs2 += blo(v.y) - a22; cs3 += bhi(v.y) - a23;
        }
        *(float4*)(o0 + 3072) = make_float4(cs0 * C25, cs1 * C25, cs2 * C25, cs3 * C25);
    }
}

__global__ __launch_bounds__(BLOCK, 6)
void wrd_kernel(const float* __restrict__ img, float* __restrict__ out) {
    __shared__ u16 sLum[96 * SL];   // 19968 B
    __shared__ u16 sT1[96 * S1];    // 16896 B
    __shared__ u16 sDC[82 * S1];    // 14432 B  (d, then comb)

    int bid = blockIdx.x, nwg = gridDim.x;
    int flat = ((nwg & 7) == 0) ? ((bid & 7) * (nwg >> 3) + (bid >> 3)) : bid;
    const int b = flat >> 8;
    const int t = flat & 255;
    const int oy = (t >> 4) * 64, ox = (t & 15) * 64;

    const float* pR = img + (size_t)b * 3145728u;
    const float* pG = pR + 1048576;
    const float* pB = pR + 2097152;
    float* po = out + (size_t)b * 1048576u;

    bool edge = (ox == 0) | (oy == 0) | (ox == 960) | (oy == 960);
    if (edge) body<true >(pR, pG, pB, po, oy, ox, threadIdx.x, sLum, sT1, sDC);
    else      body<false>(pR, pG, pB, po, oy, ox, threadIdx.x, sLum, sT1, sDC);
}

extern "C" void kernel_launch(void* const* d_in, const int* in_sizes, int n_in,
                              void* d_out, int out_size, void* d_ws, size_t ws_size,
                              hipStream_t stream) {
    const float* img = (const float*)d_in[0];
    float* out = (float*)d_out;
    int Bn = in_sizes[0] / (3 * 1024 * 1024);
    int nwg = Bn * 256;
    hipLaunchKernelGGL(wrd_kernel, dim3(nwg), dim3(BLOCK), 0, stream, img, out);
}